// Round 6
// baseline (1903.906 us; speedup 1.0000x reference)
//
#include <hip/hip_runtime.h>

#define NN 8192
#define ALPHA  0.4f
#define THETA1 0.24f   // alpha*(1-alpha)

typedef float    f32x2 __attribute__((ext_vector_type(2)));
typedef float    f32x4 __attribute__((ext_vector_type(4)));
typedef unsigned u32x2 __attribute__((ext_vector_type(2)));

__device__ __forceinline__ unsigned short f2bf(float f) {
    unsigned u = __float_as_uint(f);
    u += 0x7fffu + ((u >> 16) & 1u);      // round-to-nearest-even
    return (unsigned short)(u >> 16);
}

// ------------------------------------------------- degree + row counts
__global__ __launch_bounds__(256) void deg_count_kernel(const int* __restrict__ row,
                                                        const int* __restrict__ col,
                                                        float* __restrict__ deg,
                                                        int* __restrict__ cnt, int E) {
    int e = blockIdx.x * 256 + threadIdx.x;
    if (e >= E) return;
    unsigned r = (unsigned)row[e], c = (unsigned)col[e];
    if (r < NN && c < NN) {
        atomicAdd(&deg[c], 1.0f);     // unweighted in-degree on col (reference semantics)
        atomicAdd(&cnt[r], 1);        // CSR row count
    }
}

// ------------------------------------------------- exclusive scan (8192, one block)
__global__ __launch_bounds__(256) void scan_kernel(const int* __restrict__ cnt,
                                                   int* __restrict__ rowptr,
                                                   int* __restrict__ cursor) {
    __shared__ int sums[257];
    int t = threadIdx.x;
    int base = t * 32;
    int s = 0;
    for (int j = 0; j < 32; ++j) s += cnt[base + j];
    sums[t] = s;
    __syncthreads();
    if (t == 0) {
        int run = 0;
        for (int i = 0; i < 256; ++i) { int x = sums[i]; sums[i] = run; run += x; }
        sums[256] = run;
    }
    __syncthreads();
    int run = sums[t];
    for (int j = 0; j < 32; ++j) {
        rowptr[base + j] = run;
        cursor[base + j] = run;
        run += cnt[base + j];
    }
    if (t == 255) rowptr[NN] = sums[256];
}

// ----------------- normalized values -> dense f32 A + packed CSR fill
// packed entry: bits 0-12 = col, bits 16-31 = bf16(value)
__global__ __launch_bounds__(256) void fill_kernel(const int* __restrict__ row,
                                                   const int* __restrict__ col,
                                                   const float* __restrict__ attr,
                                                   const float* __restrict__ deg,
                                                   int* __restrict__ cursor,
                                                   unsigned* __restrict__ epk,
                                                   float* __restrict__ Af, int E) {
    int e = blockIdx.x * 256 + threadIdx.x;
    if (e >= E) return;
    unsigned r = (unsigned)row[e], c = (unsigned)col[e];
    if (r < NN && c < NN) {
        float v = rsqrtf(deg[r]) * attr[e] * rsqrtf(deg[c]);
        atomicAdd(&Af[(size_t)r * NN + c], v);             // dense A (coalesce semantics)
        int pos = atomicAdd(&cursor[r], 1);
        epk[pos] = ((unsigned)f2bf(v) << 16) | c;
    }
}

// ------------------------------------------------- f32 -> bf16 (streaming, NT)
__global__ __launch_bounds__(256) void convert_kernel(const float* __restrict__ in,
                                                      unsigned short* __restrict__ out) {
    size_t i = ((size_t)blockIdx.x * 256 + threadIdx.x) * 4;
    f32x4 v = __builtin_nontemporal_load((const f32x4*)&in[i]);
    unsigned lo = ((unsigned)f2bf(v.y) << 16) | (unsigned)f2bf(v.x);
    unsigned hi = ((unsigned)f2bf(v.w) << 16) | (unsigned)f2bf(v.z);
    u32x2 pk = {lo, hi};
    __builtin_nontemporal_store(pk, (u32x2*)&out[i]);
}

// ------------------------------------------------- SpMM: Out = A(sparse) * S(dense bf16)
// 64 col-slabs of 128 cols, XCD-dedicated (xcd = bid&7 owns 8 slabs -> 2 MB L2 window).
// Edge stream: per-lane NT chunk loads (64 edges / 256 B per wave-load) + readlane
// broadcast -> zero L2 pollution from the CSR stream; window stays L2-resident.
// FINAL=0: write bf16 A2.  FINAL=1: P = THETA1*(A + A2 + acc) + ALPHA*I  (f32).
template <int FINAL>
__global__ __launch_bounds__(256) void spmm_kernel(const int* __restrict__ rowptr,
                                                   const unsigned* __restrict__ epk,
                                                   const unsigned short* __restrict__ S,
                                                   unsigned short* __restrict__ OutBf,
                                                   float* __restrict__ P,
                                                   const unsigned short* __restrict__ Abf,
                                                   const unsigned short* __restrict__ A2bf) {
    int lane = threadIdx.x & 63;
    int wave = threadIdx.x >> 6;
    unsigned bid   = blockIdx.x;
    unsigned xcd   = bid & 7u;
    unsigned local = bid >> 3;                   // [0, 16384)
    unsigned slab  = (xcd << 3) | (local >> 11); // [0, 64), 8 slabs per XCD
    unsigned rg    = local & 2047u;              // row group [0, 2048)
    int r  = (int)(rg * 4 + wave);
    int c0 = (int)(slab << 7);                   // 128-col slab
    int e0 = __builtin_amdgcn_readfirstlane(rowptr[r]);
    int e1 = __builtin_amdgcn_readfirstlane(rowptr[r + 1]);
    const unsigned short* Sc = S + c0 + (lane << 1);   // 2 bf16 per lane = 4 B gather
    float a0 = 0.f, a1 = 0.f;

#define GATHER(u) (*(const unsigned*)(Sc + (((size_t)((u) & 0x1fffu)) << 13)))
#define ACCUM(g, u) { float vv = __uint_as_float((u) & 0xffff0000u);        \
                      a0 = fmaf(vv, __uint_as_float((g) << 16), a0);        \
                      a1 = fmaf(vv, __uint_as_float((g) & 0xffff0000u), a1); }

    int n = e1 - e0;
    for (int base = 0; base < n; base += 64) {
        int m = n - base; if (m > 64) m = 64;
        unsigned chunk = 0;
        if (lane < m) chunk = __builtin_nontemporal_load(&epk[e0 + base + lane]);
        int j = 0;
        for (; j + 4 <= m; j += 4) {             // 4 gathers in flight
            unsigned u0 = (unsigned)__builtin_amdgcn_readlane((int)chunk, j);
            unsigned u1 = (unsigned)__builtin_amdgcn_readlane((int)chunk, j + 1);
            unsigned u2 = (unsigned)__builtin_amdgcn_readlane((int)chunk, j + 2);
            unsigned u3 = (unsigned)__builtin_amdgcn_readlane((int)chunk, j + 3);
            unsigned g0 = GATHER(u0), g1 = GATHER(u1);
            unsigned g2 = GATHER(u2), g3 = GATHER(u3);
            ACCUM(g0, u0); ACCUM(g1, u1); ACCUM(g2, u2); ACCUM(g3, u3);
        }
        for (; j < m; ++j) {
            unsigned u = (unsigned)__builtin_amdgcn_readlane((int)chunk, j);
            unsigned g = GATHER(u);
            ACCUM(g, u);
        }
    }
#undef GATHER
#undef ACCUM

    size_t idx = (size_t)r * NN + c0 + (lane << 1);
    if (FINAL) {
        unsigned ab = __builtin_nontemporal_load((const unsigned*)(Abf + idx));
        unsigned bb = __builtin_nontemporal_load((const unsigned*)(A2bf + idx));
        float o0 = THETA1 * (__uint_as_float(ab << 16) + __uint_as_float(bb << 16) + a0);
        float o1 = THETA1 * (__uint_as_float(ab & 0xffff0000u) + __uint_as_float(bb & 0xffff0000u) + a1);
        int d = r - (c0 + (lane << 1));
        if (d == 0) o0 += ALPHA;
        else if (d == 1) o1 += ALPHA;
        f32x2 o = {o0, o1};
        __builtin_nontemporal_store(o, (f32x2*)(P + idx));
    } else {
        unsigned pk = ((unsigned)f2bf(a1) << 16) | (unsigned)f2bf(a0);
        __builtin_nontemporal_store(pk, (unsigned*)(OutBf + idx));
    }
}

// ------------------------------------------------------------------ launch
extern "C" void kernel_launch(void* const* d_in, const int* in_sizes, int n_in,
                              void* d_out, int out_size, void* d_ws, size_t ws_size,
                              hipStream_t stream) {
    const float* attr = (const float*)d_in[1];
    const int*   eidx = (const int*)d_in[2];
    int E = in_sizes[1];
    const int* row = eidx;
    const int* col = eidx + E;

    const size_t MAT = (size_t)NN * NN;
    unsigned short* Abf  = (unsigned short*)d_ws;            // 128 MB
    unsigned short* A2bf = Abf + MAT;                        // 128 MB
    float*    deg    = (float*)(A2bf + MAT);                 // 32 KB
    int*      cnt    = (int*)(deg + NN);                     // 32 KB
    int*      rowptr = cnt + NN;                             // (NN+2)*4
    int*      cursor = rowptr + NN + 2;                      // 32 KB
    unsigned* epk    = (unsigned*)(cursor + NN);             // E*4 B

    size_t need = MAT * 2 * sizeof(unsigned short)
                + (size_t)(NN * 4 + 2) * sizeof(int)
                + (size_t)E * sizeof(unsigned);
    if (ws_size < need) return;

    float* Af = (float*)d_out;     // f32 A staging in d_out (dead after convert)
    float* P  = (float*)d_out;     // final output overwrites it

    hipMemsetAsync(d_out, 0, MAT * sizeof(float), stream);
    hipMemsetAsync(deg, 0, NN * sizeof(float), stream);
    hipMemsetAsync(cnt, 0, NN * sizeof(int), stream);

    int eb = (E + 255) / 256;
    deg_count_kernel<<<eb, 256, 0, stream>>>(row, col, deg, cnt, E);
    scan_kernel<<<1, 256, 0, stream>>>(cnt, rowptr, cursor);
    fill_kernel<<<eb, 256, 0, stream>>>(row, col, attr, deg, cursor, epk, Af, E);
    convert_kernel<<<(int)(MAT / 1024), 256, 0, stream>>>(Af, Abf);

    const int SPMM_BLOCKS = 2048 * 64;   // (NN/4 row groups) x 64 slabs
    spmm_kernel<0><<<SPMM_BLOCKS, 256, 0, stream>>>(rowptr, epk, Abf, A2bf, nullptr, nullptr, nullptr);
    spmm_kernel<1><<<SPMM_BLOCKS, 256, 0, stream>>>(rowptr, epk, A2bf, nullptr, P, Abf, A2bf);
}

// Round 7
// 1278.582 us; speedup vs baseline: 1.4891x; 1.4891x over previous
//
#include <hip/hip_runtime.h>

#define NN 8192
#define ALPHA  0.4f
#define THETA1 0.24f   // alpha*(1-alpha)
#define SLABW  128
#define NSLAB  (NN / SLABW)            // 64
#define SLABSZ ((size_t)NN * SLABW)    // elems per slab block (1,048,576)

typedef float    f32x2 __attribute__((ext_vector_type(2)));
typedef float    f32x4 __attribute__((ext_vector_type(4)));
typedef unsigned u32x2 __attribute__((ext_vector_type(2)));

__device__ __forceinline__ unsigned short f2bf(float f) {
    unsigned u = __float_as_uint(f);
    u += 0x7fffu + ((u >> 16) & 1u);      // round-to-nearest-even
    return (unsigned short)(u >> 16);
}

// ------------------------------------------------- degree + row counts
__global__ __launch_bounds__(256) void deg_count_kernel(const int* __restrict__ row,
                                                        const int* __restrict__ col,
                                                        float* __restrict__ deg,
                                                        int* __restrict__ cnt, int E) {
    int e = blockIdx.x * 256 + threadIdx.x;
    if (e >= E) return;
    unsigned r = (unsigned)row[e], c = (unsigned)col[e];
    if (r < NN && c < NN) {
        atomicAdd(&deg[c], 1.0f);     // unweighted in-degree on col (reference semantics)
        atomicAdd(&cnt[r], 1);        // CSR row count
    }
}

// ------------------------------------------------- exclusive scan (8192, one block)
__global__ __launch_bounds__(256) void scan_kernel(const int* __restrict__ cnt,
                                                   int* __restrict__ rowptr,
                                                   int* __restrict__ cursor) {
    __shared__ int sums[257];
    int t = threadIdx.x;
    int base = t * 32;
    int s = 0;
    for (int j = 0; j < 32; ++j) s += cnt[base + j];
    sums[t] = s;
    __syncthreads();
    if (t == 0) {
        int run = 0;
        for (int i = 0; i < 256; ++i) { int x = sums[i]; sums[i] = run; run += x; }
        sums[256] = run;
    }
    __syncthreads();
    int run = sums[t];
    for (int j = 0; j < 32; ++j) {
        rowptr[base + j] = run;
        cursor[base + j] = run;
        run += cnt[base + j];
    }
    if (t == 255) rowptr[NN] = sums[256];
}

// ----------------- normalized values -> dense f32 A + packed CSR fill
// packed entry: bits 0-12 = col, bits 16-31 = bf16(value)
__global__ __launch_bounds__(256) void fill_kernel(const int* __restrict__ row,
                                                   const int* __restrict__ col,
                                                   const float* __restrict__ attr,
                                                   const float* __restrict__ deg,
                                                   int* __restrict__ cursor,
                                                   unsigned* __restrict__ epk,
                                                   float* __restrict__ Af, int E) {
    int e = blockIdx.x * 256 + threadIdx.x;
    if (e >= E) return;
    unsigned r = (unsigned)row[e], c = (unsigned)col[e];
    if (r < NN && c < NN) {
        float v = rsqrtf(deg[r]) * attr[e] * rsqrtf(deg[c]);
        atomicAdd(&Af[(size_t)r * NN + c], v);             // dense A (coalesce semantics)
        int pos = atomicAdd(&cursor[r], 1);
        epk[pos] = ((unsigned)f2bf(v) << 16) | c;
    }
}

// --------------------------- f32 row-major -> bf16 SLAB-MAJOR [64][8192][128]
// one block per row; thread t, chunk k covers cols c = k*1024 + t*4 (same slab)
__global__ __launch_bounds__(256) void convert_slab_kernel(const float* __restrict__ in,
                                                           unsigned short* __restrict__ out) {
    int r = blockIdx.x;
    int t = threadIdx.x;
    const float* rowp = in + (size_t)r * NN;
#pragma unroll
    for (int k = 0; k < 8; ++k) {
        int c = k * 1024 + t * 4;
        f32x4 v = __builtin_nontemporal_load((const f32x4*)&rowp[c]);
        unsigned lo = ((unsigned)f2bf(v.y) << 16) | (unsigned)f2bf(v.x);
        unsigned hi = ((unsigned)f2bf(v.w) << 16) | (unsigned)f2bf(v.z);
        u32x2 pk = {lo, hi};
        size_t o = (size_t)(c >> 7) * SLABSZ + (size_t)r * SLABW + (c & 127);
        __builtin_nontemporal_store(pk, (u32x2*)&out[o]);
    }
}

// ------------------------------------------------- SpMM: Out = A(sparse) * S(dense bf16)
// S is SLAB-MAJOR: slab s = contiguous 2 MB block [8192 rows][128 cols].
// XCD-dedicated slabs (xcd = bid&7 owns 8 slabs) -> contiguous window is L2-resident.
// One wave per (output row, slab); gather = base + k*256B + lane*4B.
// FINAL=0: write bf16 A2 (slab-major). FINAL=1: P = THETA1*(A+A2+acc)+ALPHA*I (f32 row-major).
template <int FINAL>
__global__ __launch_bounds__(256) void spmm_kernel(const int* __restrict__ rowptr,
                                                   const unsigned* __restrict__ epk,
                                                   const unsigned short* __restrict__ S,
                                                   unsigned short* __restrict__ OutBf,
                                                   float* __restrict__ P,
                                                   const unsigned short* __restrict__ Abf,
                                                   const unsigned short* __restrict__ A2bf) {
    int lane = threadIdx.x & 63;
    int wave = threadIdx.x >> 6;
    unsigned bid   = blockIdx.x;
    unsigned xcd   = bid & 7u;
    unsigned local = bid >> 3;                   // [0, 16384)
    unsigned slab  = (xcd << 3) | (local >> 11); // [0, 64), 8 slabs per XCD
    unsigned rg    = local & 2047u;              // row group [0, 2048)
    int r  = (int)(rg * 4 + wave);
    int e0 = __builtin_amdgcn_readfirstlane(rowptr[r]);
    int e1 = __builtin_amdgcn_readfirstlane(rowptr[r + 1]);
    const char* Sc = (const char*)(S + (size_t)slab * SLABSZ) + (lane << 2); // 4 B/lane
    float a0 = 0.f, a1 = 0.f;

#define GATHER(u) (*(const unsigned*)(Sc + (((size_t)((u) & 0x1fffu)) << 8)))
#define ACCUM(g, u) { float vv = __uint_as_float((u) & 0xffff0000u);        \
                      a0 = fmaf(vv, __uint_as_float((g) << 16), a0);        \
                      a1 = fmaf(vv, __uint_as_float((g) & 0xffff0000u), a1); }
    int e = e0;
    for (; e + 8 <= e1; e += 8) {                // 8 gathers in flight
        unsigned u0 = epk[e],     u1 = epk[e + 1];
        unsigned u2 = epk[e + 2], u3 = epk[e + 3];
        unsigned u4 = epk[e + 4], u5 = epk[e + 5];
        unsigned u6 = epk[e + 6], u7 = epk[e + 7];
        unsigned g0 = GATHER(u0), g1 = GATHER(u1), g2 = GATHER(u2), g3 = GATHER(u3);
        unsigned g4 = GATHER(u4), g5 = GATHER(u5), g6 = GATHER(u6), g7 = GATHER(u7);
        ACCUM(g0, u0); ACCUM(g1, u1); ACCUM(g2, u2); ACCUM(g3, u3);
        ACCUM(g4, u4); ACCUM(g5, u5); ACCUM(g6, u6); ACCUM(g7, u7);
    }
    for (; e < e1; ++e) {
        unsigned u = epk[e];
        unsigned g = GATHER(u);
        ACCUM(g, u);
    }
#undef GATHER
#undef ACCUM

    int cloc = lane << 1;                                  // local col in slab
    size_t idx_sm = (size_t)slab * SLABSZ + (size_t)r * SLABW + cloc;  // slab-major
    if (FINAL) {
        unsigned ab = __builtin_nontemporal_load((const unsigned*)(Abf + idx_sm));
        unsigned bb = __builtin_nontemporal_load((const unsigned*)(A2bf + idx_sm));
        float o0 = THETA1 * (__uint_as_float(ab << 16) + __uint_as_float(bb << 16) + a0);
        float o1 = THETA1 * (__uint_as_float(ab & 0xffff0000u) + __uint_as_float(bb & 0xffff0000u) + a1);
        int gc = (int)(slab << 7) + cloc;                  // global col
        int d = r - gc;
        if (d == 0) o0 += ALPHA;
        else if (d == 1) o1 += ALPHA;
        f32x2 o = {o0, o1};
        __builtin_nontemporal_store(o, (f32x2*)(P + (size_t)r * NN + gc));
    } else {
        unsigned pk = ((unsigned)f2bf(a1) << 16) | (unsigned)f2bf(a0);
        __builtin_nontemporal_store(pk, (unsigned*)(OutBf + idx_sm));
    }
}

// ------------------------------------------------------------------ launch
extern "C" void kernel_launch(void* const* d_in, const int* in_sizes, int n_in,
                              void* d_out, int out_size, void* d_ws, size_t ws_size,
                              hipStream_t stream) {
    const float* attr = (const float*)d_in[1];
    const int*   eidx = (const int*)d_in[2];
    int E = in_sizes[1];
    const int* row = eidx;
    const int* col = eidx + E;

    const size_t MAT = (size_t)NN * NN;
    unsigned short* Abf  = (unsigned short*)d_ws;            // 128 MB, slab-major
    unsigned short* A2bf = Abf + MAT;                        // 128 MB, slab-major
    float*    deg    = (float*)(A2bf + MAT);                 // 32 KB
    int*      cnt    = (int*)(deg + NN);                     // 32 KB
    int*      rowptr = cnt + NN;                             // (NN+2)*4
    int*      cursor = rowptr + NN + 2;                      // 32 KB
    unsigned* epk    = (unsigned*)(cursor + NN);             // E*4 B

    size_t need = MAT * 2 * sizeof(unsigned short)
                + (size_t)(NN * 4 + 2) * sizeof(int)
                + (size_t)E * sizeof(unsigned);
    if (ws_size < need) return;

    float* Af = (float*)d_out;     // f32 A staging in d_out (dead after convert)
    float* P  = (float*)d_out;     // final output overwrites it

    hipMemsetAsync(d_out, 0, MAT * sizeof(float), stream);
    hipMemsetAsync(deg, 0, NN * sizeof(float), stream);
    hipMemsetAsync(cnt, 0, NN * sizeof(int), stream);

    int eb = (E + 255) / 256;
    deg_count_kernel<<<eb, 256, 0, stream>>>(row, col, deg, cnt, E);
    scan_kernel<<<1, 256, 0, stream>>>(cnt, rowptr, cursor);
    fill_kernel<<<eb, 256, 0, stream>>>(row, col, attr, deg, cursor, epk, Af, E);
    convert_slab_kernel<<<NN, 256, 0, stream>>>(Af, Abf);

    const int SPMM_BLOCKS = 2048 * 64;   // (NN/4 row groups) x 64 slabs
    spmm_kernel<0><<<SPMM_BLOCKS, 256, 0, stream>>>(rowptr, epk, Abf, A2bf, nullptr, nullptr, nullptr);
    spmm_kernel<1><<<SPMM_BLOCKS, 256, 0, stream>>>(rowptr, epk, A2bf, nullptr, P, Abf, A2bf);
}